// Round 1
// baseline (279.630 us; speedup 1.0000x reference)
//
#include <hip/hip_runtime.h>

#define DS 256
#define HS 64
#define WS 64
#define BOUT 4
#define NUM 4
#define HO 192
#define WO 192

__global__ __launch_bounds__(256, 2)
void mbe_kernel(const float* __restrict__ src,
                const float* __restrict__ flow,
                const float* __restrict__ masks,
                float* __restrict__ out)
{
    const int d  = blockIdx.x;   // channel
    const int bo = blockIdx.y;   // output batch
    const int tid = threadIdx.x;

    __shared__ float img[NUM][HS * WS]; // 4 x 16KB = 64KB

    // ---- stage the 4 source images (b = n*4 + bo, channel d) into LDS ----
    #pragma unroll
    for (int n = 0; n < NUM; ++n) {
        const float4* g = (const float4*)(src + (((size_t)(n * BOUT + bo) * DS + d) * (size_t)(HS * WS)));
        float4* s = (float4*)img[n];
        #pragma unroll
        for (int it = 0; it < 4; ++it)
            s[it * 256 + tid] = g[it * 256 + tid];
    }
    __syncthreads();

    const size_t obase = ((size_t)bo * DS + d) * (size_t)(HO * WO);

    // 64x64 = 4096 (ysrc,xsrc) groups, 256 threads -> 16 groups per thread
    for (int it = 0; it < 16; ++it) {
        const int g  = it * 256 + tid;
        const int ys = g >> 6;
        const int xs = g & 63;
        const int fidx = (ys << 6) + xs;

        float acc[3][3];
        #pragma unroll
        for (int j = 0; j < 3; ++j)
            #pragma unroll
            for (int i = 0; i < 3; ++i)
                acc[j][i] = 0.0f;

        #pragma unroll
        for (int n = 0; n < NUM; ++n) {
            const int b = n * BOUT + bo;
            const float fy = flow[((size_t)(b * 2 + 0) << 12) + fidx];
            const float fx = flow[((size_t)(b * 2 + 1) << 12) + fidx];
            const float m  = masks[((size_t)b << 12) + fidx];

            const float gy = (float)ys + fy;
            const float gx = (float)xs + fx;
            const float fiy = floorf(gy);
            const float fix = floorf(gx);
            const int iy = (int)fiy;
            const int ix = (int)fix;
            const float ty = gy - fiy;   // frac in [0,1)
            const float tx = gx - fix;

            // 4x4 window rows iy-1..iy+2, cols ix-1..ix+2; zero outside bounds
            float hx[4][3];
            #pragma unroll
            for (int r = 0; r < 4; ++r) {
                const int yy = iy - 1 + r;
                const bool yv = (yy >= 0) & (yy < HS);
                const int yyc = min(max(yy, 0), HS - 1);
                float v[4];
                #pragma unroll
                for (int c = 0; c < 4; ++c) {
                    const int xx = ix - 1 + c;
                    const bool ok = yv & (xx >= 0) & (xx < WS);
                    const int xxc = min(max(xx, 0), WS - 1);
                    const float lv = img[n][yyc * WS + xxc];
                    v[c] = ok ? lv : 0.0f;
                }
                #pragma unroll
                for (int i = 0; i < 3; ++i)
                    hx[r][i] = v[i] + tx * (v[i + 1] - v[i]);
            }

            const float wy1 = m * ty;    // m * frac_y
            const float wy0 = m - wy1;   // m * (1 - frac_y)
            #pragma unroll
            for (int j = 0; j < 3; ++j)
                #pragma unroll
                for (int i = 0; i < 3; ++i)
                    acc[j][i] += wy0 * hx[j][i] + wy1 * hx[j + 1][i];
        }

        // write the 3x3 output sub-block
        #pragma unroll
        for (int j = 0; j < 3; ++j) {
            const int yo = 3 * ys + j;
            #pragma unroll
            for (int i = 0; i < 3; ++i) {
                const int xo = 3 * xs + i;
                out[obase + (size_t)yo * WO + xo] = acc[j][i];
            }
        }
    }
}

extern "C" void kernel_launch(void* const* d_in, const int* in_sizes, int n_in,
                              void* d_out, int out_size, void* d_ws, size_t ws_size,
                              hipStream_t stream) {
    const float* src   = (const float*)d_in[0];
    const float* flow  = (const float*)d_in[1];
    const float* masks = (const float*)d_in[2];
    float* out = (float*)d_out;

    dim3 grid(DS, BOUT);
    mbe_kernel<<<grid, 256, 0, stream>>>(src, flow, masks, out);
}

// Round 3
// 237.045 us; speedup vs baseline: 1.1796x; 1.1796x over previous
//
#include <hip/hip_runtime.h>

#define DS 256
#define HS 64
#define WS 64
#define BOUT 4
#define NUM 4
#define HO 192
#define WO 192
#define NTHREADS 512
#define IMG_FLOATS (NUM * HS * WS)   // 16384
#define LDS_FLOATS (IMG_FLOATS + 8)  // +4 front pad, +4 rear pad

__global__ __launch_bounds__(NTHREADS, 4)
void mbe_kernel(const float* __restrict__ src,
                const float* __restrict__ flow,
                const float* __restrict__ masks,
                float* __restrict__ out)
{
    extern __shared__ float lds[];
    float* img = lds + 4;            // img[n*4096 + y*64 + x], padded +-4 floats

    const int d  = blockIdx.x;   // channel
    const int bo = blockIdx.y;   // output batch
    const int tid = threadIdx.x;

    // ---- stage the 4 source images (b = n*4 + bo, channel d) into LDS ----
    #pragma unroll
    for (int n = 0; n < NUM; ++n) {
        const float4* g = (const float4*)(src + (((size_t)(n * BOUT + bo) * DS + d) * (size_t)(HS * WS)));
        float4* s = (float4*)(img + n * (HS * WS));
        #pragma unroll
        for (int it = 0; it < 2; ++it)
            s[it * NTHREADS + tid] = g[it * NTHREADS + tid];
    }
    __syncthreads();

    const size_t obase = ((size_t)bo * DS + d) * (size_t)(HO * WO);

    // 64x64 = 4096 (ysrc,xsrc) groups, 512 threads -> 8 groups per thread
    for (int it = 0; it < 8; ++it) {
        const int g  = it * NTHREADS + tid;
        const int ys = g >> 6;
        const int xs = g & 63;

        // hoist flow/mask loads for all 4 n (L2-resident; overlap latency)
        float fy[NUM], fx[NUM], mm[NUM];
        #pragma unroll
        for (int n = 0; n < NUM; ++n) {
            const int b = n * BOUT + bo;
            fy[n] = flow[((size_t)(b * 2 + 0) << 12) + g];
            fx[n] = flow[((size_t)(b * 2 + 1) << 12) + g];
            mm[n] = masks[((size_t)b << 12) + g];
        }

        float acc[3][3];
        #pragma unroll
        for (int j = 0; j < 3; ++j)
            #pragma unroll
            for (int i = 0; i < 3; ++i)
                acc[j][i] = 0.0f;

        #pragma unroll
        for (int n = 0; n < NUM; ++n) {
            const float gy = (float)ys + fy[n];
            const float gx = (float)xs + fx[n];
            const float fiy = floorf(gy);
            const float fix = floorf(gx);
            const int iy = (int)fiy;
            const int ix = (int)fix;
            const float ty = gy - fiy;   // frac in [0,1)
            const float tx = gx - fix;

            const int ixm1 = ix - 1;
            const int ixc  = min(max(ixm1, -3), 63);  // clamped window base col
            // column validity from the TRUE column index
            bool xv[4];
            #pragma unroll
            for (int c = 0; c < 4; ++c)
                xv[c] = ((unsigned)(ixm1 + c) < (unsigned)WS);

            const float* imgn = img + n * (HS * WS);

            float hx[4][3];
            #pragma unroll
            for (int r = 0; r < 4; ++r) {
                const int yy = iy - 1 + r;
                const bool yv = ((unsigned)yy < (unsigned)HS);
                const int yyc = min(max(yy, 0), HS - 1);
                const float* p = imgn + yyc * WS + ixc;   // 4 adjacent floats
                float v[4];
                #pragma unroll
                for (int c = 0; c < 4; ++c) {
                    const float lv = p[c];
                    v[c] = (yv & xv[c]) ? lv : 0.0f;
                }
                #pragma unroll
                for (int i = 0; i < 3; ++i)
                    hx[r][i] = v[i] + tx * (v[i + 1] - v[i]);
            }

            const float wy1 = mm[n] * ty;    // m * frac_y
            const float wy0 = mm[n] - wy1;   // m * (1 - frac_y)
            #pragma unroll
            for (int j = 0; j < 3; ++j)
                #pragma unroll
                for (int i = 0; i < 3; ++i)
                    acc[j][i] += wy0 * hx[j][i] + wy1 * hx[j + 1][i];
        }

        // write the 3x3 output sub-block
        #pragma unroll
        for (int j = 0; j < 3; ++j) {
            const int yo = 3 * ys + j;
            #pragma unroll
            for (int i = 0; i < 3; ++i) {
                const int xo = 3 * xs + i;
                out[obase + (size_t)yo * WO + xo] = acc[j][i];
            }
        }
    }
}

extern "C" void kernel_launch(void* const* d_in, const int* in_sizes, int n_in,
                              void* d_out, int out_size, void* d_ws, size_t ws_size,
                              hipStream_t stream) {
    const float* src   = (const float*)d_in[0];
    const float* flow  = (const float*)d_in[1];
    const float* masks = (const float*)d_in[2];
    float* out = (float*)d_out;

    const size_t shmem = LDS_FLOATS * sizeof(float);   // 65568 B
    static bool attr_set = false;                      // host-side, idempotent, capture-safe
    if (!attr_set) {
        hipFuncSetAttribute((const void*)mbe_kernel,
                            hipFuncAttributeMaxDynamicSharedMemorySize, (int)shmem);
        attr_set = true;
    }

    dim3 grid(DS, BOUT);
    mbe_kernel<<<grid, NTHREADS, shmem, stream>>>(src, flow, masks, out);
}